// Round 8
// baseline (451.909 us; speedup 1.0000x reference)
//
#include <hip/hip_runtime.h>
#include <hip/hip_bf16.h>
#include <stdint.h>

typedef short s8v __attribute__((ext_vector_type(8)));
typedef float f4v __attribute__((ext_vector_type(4)));

__device__ __forceinline__ void async_copy16(const void* gsrc, void* lds_dst) {
  __builtin_amdgcn_global_load_lds(
      (const __attribute__((address_space(1))) uint32_t*)(uintptr_t)gsrc,
      (__attribute__((address_space(3))) uint32_t*)(uint32_t)(uintptr_t)lds_dst,
      16, 0, 0);
}

#define WAITVM(N) asm volatile("s_waitcnt vmcnt(" #N ")" ::: "memory")
__device__ __forceinline__ void block_barrier() {
  asm volatile("" ::: "memory");
  __builtin_amdgcn_s_barrier();
  asm volatile("" ::: "memory");
}

// Device-wide barrier: all 256 blocks are provably co-resident (134.7 KB LDS -> exactly
// 1 block/CU, 256 blocks on 256 CUs). Counter zeroed by host-side hipMemsetAsync per launch.
__device__ __forceinline__ void grid_barrier(int* ctr) {
  __threadfence();          // release this block's writes (device scope)
  __syncthreads();          // all threads' fences done before arrival
  if (threadIdx.x == 0) {
    atomicAdd(ctr, 1);      // device-scope by default
    while (__hip_atomic_load(ctr, __ATOMIC_ACQUIRE, __HIP_MEMORY_SCOPE_AGENT) < 256) {
      __builtin_amdgcn_s_sleep(8);
    }
  }
  __syncthreads();
  __threadfence();          // acquire: invalidate L1 so post-barrier reads see fresh data
}

// ---------------- Fused: wpack + upsample -> [grid barrier] -> conv (r4-exact) + stats
//                   -> [grid barrier] -> BN+ReLU from registers -> single store ----------------
// grid: 256 blocks (1 per CU), 512 threads. Conv: M=512 (4 rows x 128 ow) x N=128 couts,
// MFMA 16x16x32, lA 5-slot circular row window, lB triple-buffered, counted-vmcnt rounds,
// 1 barrier/round + setprio (measured 171.6 us standalone). Fusion removes the upsample/norm
// kernels' launch gaps and norm's 134 MB out round-trip (BN applied while acc is in registers).
#define ASLOT 8448  // shorts per lA slot (132 rows * 64 ch)
__global__ __launch_bounds__(512, 2) void fused_kernel(const float* __restrict__ x,
                                                       const float* __restrict__ W,
                                                       __hip_bfloat16* __restrict__ up,
                                                       __hip_bfloat16* __restrict__ Wr,
                                                       float* __restrict__ out,
                                                       float* __restrict__ gstats,
                                                       const float* __restrict__ gamma,
                                                       const float* __restrict__ beta,
                                                       int* __restrict__ bar) {
  __shared__ __align__(16) unsigned short lA[5 * ASLOT];     //  84480 B (phase0: lx overlay)
  __shared__ __align__(16) unsigned short lB[3][128 * 64];   //  49152 B (phase0: wpack overlay)
  __shared__ float lsum[128], lssq[128];                     //   1024 B -> 134656 total

  const int tid = threadIdx.x;
  const int lane = tid & 63;
  const int wave = tid >> 6;
  const int wm = wave >> 1;   // output row within 4-row group
  const int wn = wave & 1;    // cout half
  const int lane15 = lane & 15;
  const int quad = lane >> 4;
  const int wb = wave << 6;   // wave chunk base

  const int bid = blockIdx.x;
  const int orig = ((bid & 7) << 5) | (bid >> 3);  // XCD-chunked: each XCD owns one batch image
  const int b = orig >> 5;
  const int oh0 = (orig & 31) << 2;

  // ================= PHASE 0a: weight pack (blocks 0..127), one cout per block =================
  if (bid < 128) {
    __hip_bfloat16* tw = (__hip_bfloat16*)lB;  // [ci][pos] pad 26 -> 13.3 KB
    const float* src = W + bid * 6400;
    for (int i = tid; i < 6400; i += 512) {
      int ci = i / 25;
      int pos = i - ci * 25;
      tw[ci * 26 + pos] = __float2bfloat16(src[i]);
    }
    __syncthreads();
    for (int j = tid; j < 25 * 256; j += 512) {
      int pos = j >> 8, ci = j & 255;
      Wr[pos * 32768 + bid * 256 + ci] = tw[ci * 26 + pos];
    }
  }

  // ================= PHASE 0b: upsample own 4-row slab (b, oh0..oh0+3), all 128 ow, 256 ch ====
  {
    __hip_bfloat16* lx = (__hip_bfloat16*)lA;  // [r 4][iw 64][c 64+2 pad] = 33.8 KB
    const int ih0 = (oh0 >> 1) - 1;            // may be -1 (clamped at stage)
    const int c2 = (tid & 31) * 2;
    const int owq = tid >> 5;                  // 0..15
    uint32_t* upu = (uint32_t*)up;
    for (int cb = 0; cb < 4; ++cb) {
      const int c0 = cb * 64;
      __syncthreads();  // WAR on lx
      for (int i = tid; i < 4096; i += 512) {  // 4 rows x 64 ch x 16 float4
        int c = i >> 6;
        int rem = i & 63;
        int r = rem >> 4;
        int w4 = (rem & 15) * 4;
        int gr = ih0 + r;
        gr = gr < 0 ? 0 : (gr > 63 ? 63 : gr);
        const float4 v = *(const float4*)&x[(((b * 256 + c0 + c) * 64) + gr) * 64 + w4];
        int base = (r * 64 + w4) * 66 + c;
        lx[base]       = __float2bfloat16(v.x);
        lx[base + 66]  = __float2bfloat16(v.y);
        lx[base + 132] = __float2bfloat16(v.z);
        lx[base + 198] = __float2bfloat16(v.w);
      }
      __syncthreads();
      for (int it = 0; it < 32; ++it) {  // 4 oh x 8 ow-groups; 2 ch/thread
        int oh_l = it >> 3;
        int ow = (it & 7) * 16 + owq;
        int oh = oh0 + oh_l;
        int ihA = (oh >> 1) - ((oh & 1) ^ 1);
        float wh = (oh & 1) ? 0.75f : 0.25f;
        int iwA = (ow >> 1) - ((ow & 1) ^ 1);
        float wwt = (ow & 1) ? 0.75f : 0.25f;
        int r0 = ihA - ih0;                       // 0..2 (stage rows pre-clamped)
        int w0 = iwA < 0 ? 0 : iwA;
        int w1 = iwA + 1; w1 = w1 > 63 ? 63 : w1;
        uint32_t t00 = *(const uint32_t*)&lx[(r0 * 64 + w0) * 66 + c2];
        uint32_t t01 = *(const uint32_t*)&lx[(r0 * 64 + w1) * 66 + c2];
        uint32_t t10 = *(const uint32_t*)&lx[((r0 + 1) * 64 + w0) * 66 + c2];
        uint32_t t11 = *(const uint32_t*)&lx[((r0 + 1) * 64 + w1) * 66 + c2];
        float wlo = wh * wwt, wlo1 = wh * (1.f - wwt);
        float whi = (1.f - wh) * wwt, whi1 = (1.f - wh) * (1.f - wwt);
        float vlo = wlo * __uint_as_float(t00 << 16) + wlo1 * __uint_as_float(t01 << 16) +
                    whi * __uint_as_float(t10 << 16) + whi1 * __uint_as_float(t11 << 16);
        float vhi = wlo * __uint_as_float(t00 & 0xffff0000u) + wlo1 * __uint_as_float(t01 & 0xffff0000u) +
                    whi * __uint_as_float(t10 & 0xffff0000u) + whi1 * __uint_as_float(t11 & 0xffff0000u);
        __hip_bfloat16 h0 = __float2bfloat16(vlo);
        __hip_bfloat16 h1 = __float2bfloat16(vhi);
        uint32_t pk = (uint32_t)(*(unsigned short*)&h0) | ((uint32_t)(*(unsigned short*)&h1) << 16);
        upu[((((size_t)(b * 128 + oh) * 128) + ow) * 256 + c0 + c2) >> 1] = pk;
      }
    }
  }

  grid_barrier(bar);  // up + Wr fully written and visible

  // ================= PHASE 1: conv (r4-exact core) =================
  const f4v zero4 = {0.f, 0.f, 0.f, 0.f};
  if (tid < 128) { lsum[tid] = 0.f; lssq[tid] = 0.f; }
  if (tid < 160) {  // zero kw-halo rows (0,1,130,131) of all 5 slots; never re-staged
    int s = tid >> 5, j = tid & 31;
    int rsel = j >> 3;
    int r = (rsel < 2) ? rsel : (128 + rsel);
    *(f4v*)&lA[s * ASLOT + (r * 8 + (j & 7)) * 8] = zero4;
  }

  auto stageA = [&](int slot, const __hip_bfloat16* uprow) {  // rows 2..129 (iw 0..127), 2 ops/wave
#pragma unroll
    for (int t = 0; t < 2; ++t) {
      int pl = t * 512 + wb + lane;
      int riw = pl >> 3, pc = pl & 7;
      int r = riw + 2;
      int cq = pc ^ (r & 7);
      async_copy16(uprow + riw * 256 + cq * 8, (void*)&lA[slot * ASLOT + (16 + t * 512 + wb) * 8]);
    }
  };
  auto stageB = [&](const __hip_bfloat16* wsrc, int bsel) {  // [128 cout][64 ch], 2 ops/wave
#pragma unroll
    for (int t = 0; t < 2; ++t) {
      int pl = t * 512 + wb + lane;
      int n = pl >> 3, pc = pl & 7;
      int cq = pc ^ (n & 7);
      async_copy16(wsrc + n * 256 + cq * 8, (void*)&lB[bsel][(t * 512 + wb) * 8]);
    }
  };

  f4v acc[8][4];
#pragma unroll
  for (int i = 0; i < 8; ++i)
#pragma unroll
    for (int j = 0; j < 4; ++j) acc[i][j] = zero4;

  // prologue: prime lA rows oh0-2..oh0+1 (cb=0) + lB pos0 (cb=0) into buffer 0
  for (int rr = 0; rr < 4; ++rr) {
    int ih = oh0 + rr - 2;
    if ((unsigned)ih < 128u)
      stageA(ih % 5, up + (size_t)(b * 128 + ih) * 32768);
  }
  stageB(Wr, 0);
  __syncthreads();  // drains prologue DMA + makes halo zeros / lsum init visible

  int bcur = 0;
  for (int cb = 0; cb < 4; ++cb) {
    const int c0 = cb << 6;
    for (int kh = 0; kh < 5; ++kh) {
      const int ih = oh0 + wm + kh - 2;
      const bool rowok = (unsigned)ih < 128u;
      const int abase = rowok ? (ih % 5) * ASLOT : 0;
      for (int kw = 0; kw < 5; ++kw) {
        const int pos = kh * 5 + kw;
        const int bnext = (bcur == 2) ? 0 : bcur + 1;
        if (cb != 0 && kh == 0 && kw == 0) {  // cb boundary: re-prime window at new channels
          for (int rr = 0; rr < 4; ++rr) {
            int ihn = oh0 + rr - 2;
            if ((unsigned)ihn < 128u)
              stageA(ihn % 5, up + (size_t)(b * 128 + ihn) * 32768 + c0);
          }
        }
        if (pos < 24)      stageB(Wr + (size_t)(pos + 1) * 32768 + c0, bnext);
        else if (cb < 3)   stageB(Wr + (c0 + 64), bnext);  // next cb, pos0
        const bool extraA = (kw == 2) && (kh < 4) && (oh0 + kh + 2 < 128);
        if (extraA)
          stageA((oh0 + kh + 2) % 5, up + (size_t)(b * 128 + oh0 + kh + 2) * 32768 + c0);
        if (pos == 24 && cb == 3) { WAITVM(0); }
        else if (extraA)          { WAITVM(4); }
        else                      { WAITVM(2); }
        block_barrier();
        if (rowok) {
          __builtin_amdgcn_s_setprio(1);
#pragma unroll
          for (int ks = 0; ks < 2; ++ks) {
            const int cq = ks * 4 + quad;
            s8v a[8], bb[4];
#pragma unroll
            for (int mt = 0; mt < 8; ++mt) {
              int r = mt * 16 + lane15 + kw;
              a[mt] = *(const s8v*)&lA[abase + (r * 8 + (cq ^ (r & 7))) * 8];
            }
#pragma unroll
            for (int nt = 0; nt < 4; ++nt) {
              int n = (wn << 6) + nt * 16 + lane15;
              bb[nt] = *(const s8v*)&lB[bcur][(n * 8 + (cq ^ (n & 7))) * 8];
            }
#pragma unroll
            for (int mt = 0; mt < 8; ++mt)
#pragma unroll
              for (int nt = 0; nt < 4; ++nt)
                acc[mt][nt] = __builtin_amdgcn_mfma_f32_16x16x32_bf16(a[mt], bb[nt], acc[mt][nt], 0, 0, 0);
          }
          __builtin_amdgcn_s_setprio(0);
        }
        if (pos == 24 && cb < 3) block_barrier();  // protect cb-boundary lA re-prime (WAR)
        bcur = bnext;
      }
    }
  }

  // ---- stats from acc (D: cout=lane&15, ow=mt*16+quad*4+reg) ----
#pragma unroll
  for (int nt = 0; nt < 4; ++nt) {
    const int n = (wn << 6) + nt * 16 + lane15;
    float s = 0.f, ss = 0.f;
#pragma unroll
    for (int mt = 0; mt < 8; ++mt) {
      f4v v = acc[mt][nt];
      s += v.x + v.y + v.z + v.w;
      ss += v.x * v.x + v.y * v.y + v.z * v.z + v.w * v.w;
    }
    s += __shfl_xor(s, 16, 64); ss += __shfl_xor(ss, 16, 64);
    s += __shfl_xor(s, 32, 64); ss += __shfl_xor(ss, 32, 64);
    if (quad == 0) { atomicAdd(&lsum[n], s); atomicAdd(&lssq[n], ss); }
  }
  __syncthreads();
  if (tid < 128) {
    atomicAdd(&gstats[tid], lsum[tid]);
    atomicAdd(&gstats[128 + tid], lssq[tid]);
  }

  grid_barrier(bar + 1);  // all partial stats accumulated and visible

  // ================= PHASE 2: BN + ReLU applied to acc in registers, single store =================
  const int oh = oh0 + wm;
#pragma unroll
  for (int nt = 0; nt < 4; ++nt) {
    const int n = (wn << 6) + nt * 16 + lane15;
    float mean = gstats[n] * (1.f / 131072.f);
    float var = gstats[128 + n] * (1.f / 131072.f) - mean * mean;
    float sc = gamma[n] * rsqrtf(var + 1e-5f);
    float bi = beta[n] - mean * sc;
    float* oc = out + ((size_t)(b * 128 + n) * 128 + oh) * 128;
#pragma unroll
    for (int mt = 0; mt < 8; ++mt) {
      f4v v = acc[mt][nt];
      v.x = fmaxf(fmaf(v.x, sc, bi), 0.f);
      v.y = fmaxf(fmaf(v.y, sc, bi), 0.f);
      v.z = fmaxf(fmaf(v.z, sc, bi), 0.f);
      v.w = fmaxf(fmaf(v.w, sc, bi), 0.f);
      *(f4v*)&oc[mt * 16 + (quad << 2)] = v;
    }
  }
}

extern "C" void kernel_launch(void* const* d_in, const int* in_sizes, int n_in,
                              void* d_out, int out_size, void* d_ws, size_t ws_size,
                              hipStream_t stream) {
  (void)in_sizes; (void)n_in; (void)out_size; (void)ws_size;
  const float* x = (const float*)d_in[0];
  const float* W = (const float*)d_in[1];
  const float* gamma = (const float*)d_in[2];
  const float* beta = (const float*)d_in[3];
  float* out = (float*)d_out;
  char* ws = (char*)d_ws;
  __hip_bfloat16* up = (__hip_bfloat16*)ws;                       // 67,108,864 B
  __hip_bfloat16* Wr = (__hip_bfloat16*)(ws + 67108864);          // 1,638,400 B
  float* gstats = (float*)(ws + 67108864 + 1638400);              // sum[128], ssq[128]
  int* bar = (int*)(gstats + 256);                                // 2 barrier counters

  hipMemsetAsync(gstats, 0, 256 * sizeof(float) + 2 * sizeof(int), stream);
  fused_kernel<<<256, 512, 0, stream>>>(x, W, up, Wr, out, gstats, gamma, beta, bar);
}

// Round 9
// 350.514 us; speedup vs baseline: 1.2893x; 1.2893x over previous
//
#include <hip/hip_runtime.h>
#include <hip/hip_bf16.h>
#include <stdint.h>

typedef short s8v __attribute__((ext_vector_type(8)));
typedef float f4v __attribute__((ext_vector_type(4)));

__device__ __forceinline__ void async_copy16(const void* gsrc, void* lds_dst) {
  __builtin_amdgcn_global_load_lds(
      (const __attribute__((address_space(1))) uint32_t*)(uintptr_t)gsrc,
      (__attribute__((address_space(3))) uint32_t*)(uint32_t)(uintptr_t)lds_dst,
      16, 0, 0);
}

#define WAITVM(N) asm volatile("s_waitcnt vmcnt(" #N ")" ::: "memory")
__device__ __forceinline__ void block_barrier() {
  asm volatile("" ::: "memory");
  __builtin_amdgcn_s_barrier();
  asm volatile("" ::: "memory");
}

// Device-wide barrier: all 256 blocks are co-resident (134.7 KB LDS -> exactly 1 block/CU,
// grid = 256 = CU count). Counter zeroed by host-side hipMemsetAsync each launch/replay.
__device__ __forceinline__ void grid_barrier(int* ctr) {
  __threadfence();          // release this block's writes (device scope)
  __syncthreads();          // all threads' fences done before arrival
  if (threadIdx.x == 0) {
    atomicAdd(ctr, 1);      // device-scope by default
    while (__hip_atomic_load(ctr, __ATOMIC_ACQUIRE, __HIP_MEMORY_SCOPE_AGENT) < 256) {
      __builtin_amdgcn_s_sleep(8);
    }
  }
  __syncthreads();
  __threadfence();          // acquire: invalidate L1 so post-barrier reads see fresh data
}

// ---------------- W pack: [co][ci][kh][kw] fp32 -> [kh*5+kw][co][ci] bf16 ----------------
__global__ __launch_bounds__(256) void wpack_kernel(const float* __restrict__ W,
                                                    __hip_bfloat16* __restrict__ Wr) {
  __shared__ __hip_bfloat16 t[256 * 26];  // [ci][pos], pad to 26
  const int co = blockIdx.x;
  const int tid = threadIdx.x;
  const float* src = W + co * 6400;
  for (int i = tid; i < 6400; i += 256) {
    int ci = i / 25;
    int pos = i - ci * 25;
    t[ci * 26 + pos] = __float2bfloat16(src[i]);
  }
  __syncthreads();
  for (int pos = 0; pos < 25; ++pos)
    Wr[pos * 32768 + co * 256 + tid] = t[tid * 26 + pos];
}

// ---------------- Upsample: x NCHW fp32 (8,256,64,64) -> up NHWC bf16 (8,128,128,256) ----------------
// grid: b(8) x cb(4,64ch) x ohb(16,8 rows) x owb(2,64 cols) = 1024 blocks (4/CU, 37 KB LDS)
__global__ __launch_bounds__(256) void upsample_kernel(const float* __restrict__ x,
                                                       __hip_bfloat16* __restrict__ up) {
  __shared__ __hip_bfloat16 lx[6 * 48 * 66];  // [ih 6][iw 48][c 64 + 2 pad] = 38016 B
  const int tid = threadIdx.x;
  const int bx = blockIdx.x;
  const int owb = bx & 1;
  const int ohb = (bx >> 1) & 15;
  const int cb = (bx >> 5) & 3;
  const int b = bx >> 7;
  const int oh0 = ohb * 8, ow0 = owb * 64, c0 = cb * 64;
  const int ih0 = (oh0 >> 1) - 1;                    // may be -1
  const int iw_lo = (ow0 >> 1) - 1;
  const int aligned = (iw_lo < 0 ? 0 : iw_lo) & ~15; // 0 or 16

  for (int i = tid; i < 64 * 6 * 12; i += 256) {     // float4 loads along iw
    int c = i / 72;
    int rem = i - c * 72;
    int r = rem / 12;
    int w4 = (rem - r * 12) * 4;
    int gr = ih0 + r;
    gr = gr < 0 ? 0 : (gr > 63 ? 63 : gr);
    const float4 v = *(const float4*)&x[(((b * 256 + c0 + c) * 64) + gr) * 64 + aligned + w4];
    int base = (r * 48 + w4) * 66 + c;
    lx[base]       = __float2bfloat16(v.x);
    lx[base + 66]  = __float2bfloat16(v.y);
    lx[base + 132] = __float2bfloat16(v.z);
    lx[base + 198] = __float2bfloat16(v.w);
  }
  __syncthreads();

  // 2 channels per thread: b32 LDS reads, packed bf16x2 global stores
  const int c2 = (tid & 31) * 2;
  const int owq = tid >> 5;  // 0..7
  uint32_t* upu = (uint32_t*)up;
  for (int it = 0; it < 64; ++it) {
    int oh_l = it >> 3;
    int ow_l = (it & 7) * 8 + owq;
    int oh = oh0 + oh_l, ow = ow0 + ow_l;
    int ihA = (oh >> 1) - ((oh & 1) ^ 1);            // first tap row
    float wh = (oh & 1) ? 0.75f : 0.25f;             // its weight
    int iwA = (ow >> 1) - ((ow & 1) ^ 1);
    float wwt = (ow & 1) ? 0.75f : 0.25f;
    int r0 = ihA - ih0;                               // slot content is pre-clamped
    int w0 = (iwA < 0 ? 0 : iwA) - aligned;
    int w1t = iwA + 1; w1t = w1t > 63 ? 63 : w1t;
    int w1 = w1t - aligned;
    uint32_t t00 = *(const uint32_t*)&lx[(r0 * 48 + w0) * 66 + c2];
    uint32_t t01 = *(const uint32_t*)&lx[(r0 * 48 + w1) * 66 + c2];
    uint32_t t10 = *(const uint32_t*)&lx[((r0 + 1) * 48 + w0) * 66 + c2];
    uint32_t t11 = *(const uint32_t*)&lx[((r0 + 1) * 48 + w1) * 66 + c2];
    float wlo = wh * wwt, wlo1 = wh * (1.f - wwt);
    float whi = (1.f - wh) * wwt, whi1 = (1.f - wh) * (1.f - wwt);
    float vlo = wlo * __uint_as_float(t00 << 16) + wlo1 * __uint_as_float(t01 << 16) +
                whi * __uint_as_float(t10 << 16) + whi1 * __uint_as_float(t11 << 16);
    float vhi = wlo * __uint_as_float(t00 & 0xffff0000u) + wlo1 * __uint_as_float(t01 & 0xffff0000u) +
                whi * __uint_as_float(t10 & 0xffff0000u) + whi1 * __uint_as_float(t11 & 0xffff0000u);
    __hip_bfloat16 h0 = __float2bfloat16(vlo);
    __hip_bfloat16 h1 = __float2bfloat16(vhi);
    uint32_t pk = (uint32_t)(*(unsigned short*)&h0) | ((uint32_t)(*(unsigned short*)&h1) << 16);
    upu[((((size_t)(b * 128 + oh) * 128) + ow) * 256 + c0 + c2) >> 1] = pk;
  }
}

// ---------------- Conv: r4-exact core (171.6 us) + fused BN/ReLU epilogue via grid barrier ----------------
// grid: 256 blocks (1 per CU) = b(8) x ohg(32), 512 threads (8 waves: 4 rows x 2 cout-halves).
// lA: 5-slot circular row window [132 iw+halo][64 ch] XOR-swizzled; prefetch at kw==2.
// lB: triple-buffered; round r reads r%3, stages (r+2)%3. One barrier/round, counted vmcnt.
// Epilogue: stats only -> grid barrier -> BN+ReLU applied to acc in regs -> single out store
// (removes the separate norm kernel's 134 MB round-trip + launch gap).
#define ASLOT 8448  // shorts per lA slot (132 rows * 64 ch)
__global__ __launch_bounds__(512, 2) void conv_kernel(const __hip_bfloat16* __restrict__ up,
                                                      const __hip_bfloat16* __restrict__ Wr,
                                                      float* __restrict__ out,
                                                      float* __restrict__ gstats,
                                                      const float* __restrict__ gamma,
                                                      const float* __restrict__ beta,
                                                      int* __restrict__ bar) {
  __shared__ __align__(16) unsigned short lA[5 * ASLOT];     //  84480 B
  __shared__ __align__(16) unsigned short lB[3][128 * 64];   //  49152 B
  __shared__ float lsum[128], lssq[128];                     //   1024 B -> 134656 total

  const int tid = threadIdx.x;
  const int lane = tid & 63;
  const int wave = tid >> 6;
  const int wm = wave >> 1;   // output row within 4-row group
  const int wn = wave & 1;    // cout half
  const int lane15 = lane & 15;
  const int quad = lane >> 4;
  const int wb = wave << 6;   // wave chunk base

  const int bid = blockIdx.x;
  const int orig = ((bid & 7) << 5) | (bid >> 3);  // XCD-chunked: each XCD owns one batch image
  const int b = orig >> 5;
  const int oh0 = (orig & 31) << 2;

  const f4v zero4 = {0.f, 0.f, 0.f, 0.f};
  if (tid < 128) { lsum[tid] = 0.f; lssq[tid] = 0.f; }
  // zero kw-halo rows (0,1,130,131 <-> iw -2,-1,128,129) of all 5 slots; never re-staged
  if (tid < 160) {
    int s = tid >> 5, j = tid & 31;
    int rsel = j >> 3;
    int r = (rsel < 2) ? rsel : (128 + rsel);
    *(f4v*)&lA[s * ASLOT + (r * 8 + (j & 7)) * 8] = zero4;
  }

  auto stageA = [&](int slot, const __hip_bfloat16* uprow) {  // rows 2..129 (iw 0..127), 2 ops/wave
#pragma unroll
    for (int t = 0; t < 2; ++t) {
      int pl = t * 512 + wb + lane;  // 0..1023
      int riw = pl >> 3, pc = pl & 7;
      int r = riw + 2;
      int cq = pc ^ (r & 7);
      async_copy16(uprow + riw * 256 + cq * 8, (void*)&lA[slot * ASLOT + (16 + t * 512 + wb) * 8]);
    }
  };
  auto stageB = [&](const __hip_bfloat16* wsrc, int bsel) {  // [128 cout][64 ch], 2 ops/wave
#pragma unroll
    for (int t = 0; t < 2; ++t) {
      int pl = t * 512 + wb + lane;
      int n = pl >> 3, pc = pl & 7;
      int cq = pc ^ (n & 7);
      async_copy16(wsrc + n * 256 + cq * 8, (void*)&lB[bsel][(t * 512 + wb) * 8]);
    }
  };

  f4v acc[8][4];
#pragma unroll
  for (int i = 0; i < 8; ++i)
#pragma unroll
    for (int j = 0; j < 4; ++j) acc[i][j] = zero4;

  // ---- prologue: prime lA rows oh0-2..oh0+1 (cb=0) + lB pos0 (cb=0) into buffer 0
  for (int rr = 0; rr < 4; ++rr) {
    int ih = oh0 + rr - 2;
    if ((unsigned)ih < 128u)
      stageA(ih % 5, up + (size_t)(b * 128 + ih) * 32768);
  }
  stageB(Wr, 0);
  __syncthreads();  // drains prologue DMA + makes halo zeros / lsum init visible (one-time)

  int bcur = 0;
  for (int cb = 0; cb < 4; ++cb) {
    const int c0 = cb << 6;
    for (int kh = 0; kh < 5; ++kh) {
      const int ih = oh0 + wm + kh - 2;
      const bool rowok = (unsigned)ih < 128u;
      const int abase = rowok ? (ih % 5) * ASLOT : 0;
      for (int kw = 0; kw < 5; ++kw) {
        const int pos = kh * 5 + kw;
        const int bnext = (bcur == 2) ? 0 : bcur + 1;
        // ---- stage phase ----
        if (cb != 0 && kh == 0 && kw == 0) {  // cb boundary: re-prime window at new channels
          for (int rr = 0; rr < 4; ++rr) {    // issued FIRST so WAITVM(2) below drains them
            int ihn = oh0 + rr - 2;
            if ((unsigned)ihn < 128u)
              stageA(ihn % 5, up + (size_t)(b * 128 + ihn) * 32768 + c0);
          }
        }
        if (pos < 24)      stageB(Wr + (size_t)(pos + 1) * 32768 + c0, bnext);
        else if (cb < 3)   stageB(Wr + (c0 + 64), bnext);  // next cb, pos0
        const bool extraA = (kw == 2) && (kh < 4) && (oh0 + kh + 2 < 128);
        if (extraA)  // lA row for kh+1; target slot disjoint from rounds r-1..r read sets
          stageA((oh0 + kh + 2) % 5, up + (size_t)(b * 128 + oh0 + kh + 2) * 32768 + c0);
        // ---- counted wait (this round's ops stay in flight) + single barrier ----
        if (pos == 24 && cb == 3) { WAITVM(0); }
        else if (extraA)          { WAITVM(4); }
        else                      { WAITVM(2); }
        block_barrier();
        // ---- compute (prioritized) ----
        if (rowok) {
          __builtin_amdgcn_s_setprio(1);
#pragma unroll
          for (int ks = 0; ks < 2; ++ks) {
            const int cq = ks * 4 + quad;
            s8v a[8], bb[4];
#pragma unroll
            for (int mt = 0; mt < 8; ++mt) {
              int r = mt * 16 + lane15 + kw;  // shifted by kw; halo rows are zero
              a[mt] = *(const s8v*)&lA[abase + (r * 8 + (cq ^ (r & 7))) * 8];
            }
#pragma unroll
            for (int nt = 0; nt < 4; ++nt) {
              int n = (wn << 6) + nt * 16 + lane15;
              bb[nt] = *(const s8v*)&lB[bcur][(n * 8 + (cq ^ (n & 7))) * 8];
            }
#pragma unroll
            for (int mt = 0; mt < 8; ++mt)
#pragma unroll
              for (int nt = 0; nt < 4; ++nt)
                acc[mt][nt] = __builtin_amdgcn_mfma_f32_16x16x32_bf16(a[mt], bb[nt], acc[mt][nt], 0, 0, 0);
          }
          __builtin_amdgcn_s_setprio(0);
        }
        if (pos == 24 && cb < 3) block_barrier();  // protect cb-boundary lA re-prime (WAR)
        bcur = bnext;
      }
    }
  }

  // ---- stats from acc (D: cout=lane&15, ow=mt*16+quad*4+reg); no out store yet ----
#pragma unroll
  for (int nt = 0; nt < 4; ++nt) {
    const int n = (wn << 6) + nt * 16 + lane15;
    float s = 0.f, ss = 0.f;
#pragma unroll
    for (int mt = 0; mt < 8; ++mt) {
      f4v v = acc[mt][nt];
      s += v.x + v.y + v.z + v.w;
      ss += v.x * v.x + v.y * v.y + v.z * v.z + v.w * v.w;
    }
    s += __shfl_xor(s, 16, 64); ss += __shfl_xor(ss, 16, 64);
    s += __shfl_xor(s, 32, 64); ss += __shfl_xor(ss, 32, 64);
    if (quad == 0) { atomicAdd(&lsum[n], s); atomicAdd(&lssq[n], ss); }
  }
  __syncthreads();
  if (tid < 128) {
    atomicAdd(&gstats[tid], lsum[tid]);
    atomicAdd(&gstats[128 + tid], lssq[tid]);
  }

  grid_barrier(bar);  // all partial stats accumulated and visible

  // ---- BN + ReLU applied to acc in registers, single out store ----
  const int oh = oh0 + wm;
#pragma unroll
  for (int nt = 0; nt < 4; ++nt) {
    const int n = (wn << 6) + nt * 16 + lane15;
    float mean = gstats[n] * (1.f / 131072.f);
    float var = gstats[128 + n] * (1.f / 131072.f) - mean * mean;
    float sc = gamma[n] * rsqrtf(var + 1e-5f);
    float bi = beta[n] - mean * sc;
    float* oc = out + ((size_t)(b * 128 + n) * 128 + oh) * 128;
#pragma unroll
    for (int mt = 0; mt < 8; ++mt) {
      f4v v = acc[mt][nt];
      v.x = fmaxf(fmaf(v.x, sc, bi), 0.f);
      v.y = fmaxf(fmaf(v.y, sc, bi), 0.f);
      v.z = fmaxf(fmaf(v.z, sc, bi), 0.f);
      v.w = fmaxf(fmaf(v.w, sc, bi), 0.f);
      *(f4v*)&oc[mt * 16 + (quad << 2)] = v;
    }
  }
}

extern "C" void kernel_launch(void* const* d_in, const int* in_sizes, int n_in,
                              void* d_out, int out_size, void* d_ws, size_t ws_size,
                              hipStream_t stream) {
  (void)in_sizes; (void)n_in; (void)out_size; (void)ws_size;
  const float* x = (const float*)d_in[0];
  const float* W = (const float*)d_in[1];
  const float* gamma = (const float*)d_in[2];
  const float* beta = (const float*)d_in[3];
  float* out = (float*)d_out;
  char* ws = (char*)d_ws;
  __hip_bfloat16* up = (__hip_bfloat16*)ws;                       // 67,108,864 B
  __hip_bfloat16* Wr = (__hip_bfloat16*)(ws + 67108864);          // 1,638,400 B
  float* gstats = (float*)(ws + 67108864 + 1638400);              // sum[128], ssq[128]
  int* bar = (int*)(gstats + 256);                                // 1 barrier counter

  hipMemsetAsync(gstats, 0, 256 * sizeof(float) + sizeof(int), stream);
  wpack_kernel<<<128, 256, 0, stream>>>(W, Wr);
  upsample_kernel<<<1024, 256, 0, stream>>>(x, up);
  conv_kernel<<<256, 512, 0, stream>>>(up, Wr, out, gstats, gamma, beta, bar);
}

// Round 10
// 290.801 us; speedup vs baseline: 1.5540x; 1.2053x over previous
//
#include <hip/hip_runtime.h>
#include <hip/hip_bf16.h>
#include <stdint.h>

typedef short s8v __attribute__((ext_vector_type(8)));
typedef float f4v __attribute__((ext_vector_type(4)));

__device__ __forceinline__ void async_copy16(const void* gsrc, void* lds_dst) {
  __builtin_amdgcn_global_load_lds(
      (const __attribute__((address_space(1))) uint32_t*)(uintptr_t)gsrc,
      (__attribute__((address_space(3))) uint32_t*)(uint32_t)(uintptr_t)lds_dst,
      16, 0, 0);
}

#define WAITVM(N) asm volatile("s_waitcnt vmcnt(" #N ")" ::: "memory")
__device__ __forceinline__ void block_barrier() {
  asm volatile("" ::: "memory");
  __builtin_amdgcn_s_barrier();
  asm volatile("" ::: "memory");
}

// ---------------- Upsample (+ fused wpack + gstats zero): ----------------
// x NCHW fp32 (8,256,64,64) -> up NHWC bf16 (8,128,128,256)
// grid: b(8) x cb(4,64ch) x ohb(16,8 rows) x owb(2,64 cols) = 1024 blocks (~4/CU, 38 KB LDS).
// Blocks 0..127 additionally pack W for cout=bid: [co][ci][kh][kw] f32 -> [pos][co][ci] bf16
// (reuses the lx LDS before upsample staging); block 0 zeroes gstats.
__global__ __launch_bounds__(256) void upsample_kernel(const float* __restrict__ x,
                                                       __hip_bfloat16* __restrict__ up,
                                                       const float* __restrict__ W,
                                                       __hip_bfloat16* __restrict__ Wr,
                                                       float* __restrict__ gstats) {
  __shared__ __hip_bfloat16 lx[6 * 48 * 66];  // [ih 6][iw 48][c 64 + 2 pad] = 38016 B
  const int tid = threadIdx.x;
  const int bx = blockIdx.x;

  if (bx == 0 && tid < 256) gstats[tid] = 0.f;  // sum[128], ssq[128]
  if (bx < 128) {  // wpack for cout = bx
    __hip_bfloat16* tw = lx;  // [ci][pos] pad 26 = 13.3 KB
    const float* src = W + bx * 6400;
    for (int i = tid; i < 6400; i += 256) {
      int ci = i / 25;
      int pos = i - ci * 25;
      tw[ci * 26 + pos] = __float2bfloat16(src[i]);
    }
    __syncthreads();
    for (int pos = 0; pos < 25; ++pos)
      Wr[pos * 32768 + bx * 256 + tid] = tw[tid * 26 + pos];
    __syncthreads();  // lx reused below
  }

  const int owb = bx & 1;
  const int ohb = (bx >> 1) & 15;
  const int cb = (bx >> 5) & 3;
  const int b = bx >> 7;
  const int oh0 = ohb * 8, ow0 = owb * 64, c0 = cb * 64;
  const int ih0 = (oh0 >> 1) - 1;                    // may be -1
  const int iw_lo = (ow0 >> 1) - 1;
  const int aligned = (iw_lo < 0 ? 0 : iw_lo) & ~15; // 0 or 16

  for (int i = tid; i < 64 * 6 * 12; i += 256) {     // float4 loads along iw
    int c = i / 72;
    int rem = i - c * 72;
    int r = rem / 12;
    int w4 = (rem - r * 12) * 4;
    int gr = ih0 + r;
    gr = gr < 0 ? 0 : (gr > 63 ? 63 : gr);
    const float4 v = *(const float4*)&x[(((b * 256 + c0 + c) * 64) + gr) * 64 + aligned + w4];
    int base = (r * 48 + w4) * 66 + c;
    lx[base]       = __float2bfloat16(v.x);
    lx[base + 66]  = __float2bfloat16(v.y);
    lx[base + 132] = __float2bfloat16(v.z);
    lx[base + 198] = __float2bfloat16(v.w);
  }
  __syncthreads();

  // 2 channels per thread: b32 LDS reads, packed bf16x2 global stores
  const int c2 = (tid & 31) * 2;
  const int owq = tid >> 5;  // 0..7
  uint32_t* upu = (uint32_t*)up;
  for (int it = 0; it < 64; ++it) {
    int oh_l = it >> 3;
    int ow_l = (it & 7) * 8 + owq;
    int oh = oh0 + oh_l, ow = ow0 + ow_l;
    int ihA = (oh >> 1) - ((oh & 1) ^ 1);            // first tap row
    float wh = (oh & 1) ? 0.75f : 0.25f;             // its weight
    int iwA = (ow >> 1) - ((ow & 1) ^ 1);
    float wwt = (ow & 1) ? 0.75f : 0.25f;
    int r0 = ihA - ih0;                               // slot content is pre-clamped
    int w0 = (iwA < 0 ? 0 : iwA) - aligned;
    int w1t = iwA + 1; w1t = w1t > 63 ? 63 : w1t;
    int w1 = w1t - aligned;
    uint32_t t00 = *(const uint32_t*)&lx[(r0 * 48 + w0) * 66 + c2];
    uint32_t t01 = *(const uint32_t*)&lx[(r0 * 48 + w1) * 66 + c2];
    uint32_t t10 = *(const uint32_t*)&lx[((r0 + 1) * 48 + w0) * 66 + c2];
    uint32_t t11 = *(const uint32_t*)&lx[((r0 + 1) * 48 + w1) * 66 + c2];
    float wlo = wh * wwt, wlo1 = wh * (1.f - wwt);
    float whi = (1.f - wh) * wwt, whi1 = (1.f - wh) * (1.f - wwt);
    float vlo = wlo * __uint_as_float(t00 << 16) + wlo1 * __uint_as_float(t01 << 16) +
                whi * __uint_as_float(t10 << 16) + whi1 * __uint_as_float(t11 << 16);
    float vhi = wlo * __uint_as_float(t00 & 0xffff0000u) + wlo1 * __uint_as_float(t01 & 0xffff0000u) +
                whi * __uint_as_float(t10 & 0xffff0000u) + whi1 * __uint_as_float(t11 & 0xffff0000u);
    __hip_bfloat16 h0 = __float2bfloat16(vlo);
    __hip_bfloat16 h1 = __float2bfloat16(vhi);
    uint32_t pk = (uint32_t)(*(unsigned short*)&h0) | ((uint32_t)(*(unsigned short*)&h1) << 16);
    upu[((((size_t)(b * 128 + oh) * 128) + ow) * 256 + c0 + c2) >> 1] = pk;
  }
}

// ---------------- Conv: implicit GEMM, M=512 (4 rows x 128 ow) x N=128 couts, MFMA bf16 ----------------
// r4-verified core (171.6 us standalone): 256 blocks (1/CU) = b(8) x ohg(32), 512 threads
// (8 waves: 4 rows x 2 cout-halves). lA: 5-slot circular row window [132 iw+halo][64 ch]
// XOR-swizzled; prefetch at kw==2. lB: triple-buffered; round r reads r%3, stages (r+1)%3.
// One barrier/round, counted vmcnt (never drain mid-loop), setprio around MFMA cluster.
#define ASLOT 8448  // shorts per lA slot (132 rows * 64 ch)
__global__ __launch_bounds__(512, 2) void conv_kernel(const __hip_bfloat16* __restrict__ up,
                                                      const __hip_bfloat16* __restrict__ Wr,
                                                      float* __restrict__ out,
                                                      float* __restrict__ gstats) {
  __shared__ __align__(16) unsigned short lA[5 * ASLOT];     // 84480 B
  __shared__ __align__(16) unsigned short lB[3][128 * 64];   // 49152 B
  __shared__ float lsum[128], lssq[128];

  const int tid = threadIdx.x;
  const int lane = tid & 63;
  const int wave = tid >> 6;
  const int wm = wave >> 1;   // output row within 4-row group
  const int wn = wave & 1;    // cout half
  const int lane15 = lane & 15;
  const int quad = lane >> 4;
  const int wb = wave << 6;   // wave chunk base

  const int bid = blockIdx.x;
  const int orig = ((bid & 7) << 5) | (bid >> 3);  // XCD-chunked: each XCD owns one batch image
  const int b = orig >> 5;
  const int oh0 = (orig & 31) << 2;

  const f4v zero4 = {0.f, 0.f, 0.f, 0.f};
  if (tid < 128) { lsum[tid] = 0.f; lssq[tid] = 0.f; }
  // zero kw-halo rows (0,1,130,131 <-> iw -2,-1,128,129) of all 5 slots; never re-staged
  if (tid < 160) {
    int s = tid >> 5, j = tid & 31;
    int rsel = j >> 3;
    int r = (rsel < 2) ? rsel : (128 + rsel);
    *(f4v*)&lA[s * ASLOT + (r * 8 + (j & 7)) * 8] = zero4;
  }

  auto stageA = [&](int slot, const __hip_bfloat16* uprow) {  // rows 2..129 (iw 0..127), 2 ops/wave
#pragma unroll
    for (int t = 0; t < 2; ++t) {
      int pl = t * 512 + wb + lane;  // 0..1023
      int riw = pl >> 3, pc = pl & 7;
      int r = riw + 2;
      int cq = pc ^ (r & 7);
      async_copy16(uprow + riw * 256 + cq * 8, (void*)&lA[slot * ASLOT + (16 + t * 512 + wb) * 8]);
    }
  };
  auto stageB = [&](const __hip_bfloat16* wsrc, int bsel) {  // [128 cout][64 ch], 2 ops/wave
#pragma unroll
    for (int t = 0; t < 2; ++t) {
      int pl = t * 512 + wb + lane;
      int n = pl >> 3, pc = pl & 7;
      int cq = pc ^ (n & 7);
      async_copy16(wsrc + n * 256 + cq * 8, (void*)&lB[bsel][(t * 512 + wb) * 8]);
    }
  };

  f4v acc[8][4];
#pragma unroll
  for (int i = 0; i < 8; ++i)
#pragma unroll
    for (int j = 0; j < 4; ++j) acc[i][j] = zero4;

  // ---- prologue: prime lA rows oh0-2..oh0+1 (cb=0) + lB pos0 (cb=0) into buffer 0
  for (int rr = 0; rr < 4; ++rr) {
    int ih = oh0 + rr - 2;
    if ((unsigned)ih < 128u)
      stageA(ih % 5, up + (size_t)(b * 128 + ih) * 32768);
  }
  stageB(Wr, 0);
  __syncthreads();  // drains prologue DMA + makes halo zeros / lsum init visible (one-time)

  int bcur = 0;
  for (int cb = 0; cb < 4; ++cb) {
    const int c0 = cb << 6;
    for (int kh = 0; kh < 5; ++kh) {
      const int ih = oh0 + wm + kh - 2;
      const bool rowok = (unsigned)ih < 128u;
      const int abase = rowok ? (ih % 5) * ASLOT : 0;
      for (int kw = 0; kw < 5; ++kw) {
        const int pos = kh * 5 + kw;
        const int bnext = (bcur == 2) ? 0 : bcur + 1;
        // ---- stage phase ----
        if (cb != 0 && kh == 0 && kw == 0) {  // cb boundary: re-prime window at new channels
          for (int rr = 0; rr < 4; ++rr) {    // issued FIRST so WAITVM(2) below drains them
            int ihn = oh0 + rr - 2;
            if ((unsigned)ihn < 128u)
              stageA(ihn % 5, up + (size_t)(b * 128 + ihn) * 32768 + c0);
          }
        }
        if (pos < 24)      stageB(Wr + (size_t)(pos + 1) * 32768 + c0, bnext);
        else if (cb < 3)   stageB(Wr + (c0 + 64), bnext);  // next cb, pos0
        const bool extraA = (kw == 2) && (kh < 4) && (oh0 + kh + 2 < 128);
        if (extraA)  // lA row for kh+1; target slot disjoint from rounds r-1..r read sets
          stageA((oh0 + kh + 2) % 5, up + (size_t)(b * 128 + oh0 + kh + 2) * 32768 + c0);
        // ---- counted wait (this round's ops stay in flight) + single barrier ----
        if (pos == 24 && cb == 3) { WAITVM(0); }
        else if (extraA)          { WAITVM(4); }
        else                      { WAITVM(2); }
        block_barrier();
        // ---- compute (prioritized) ----
        if (rowok) {
          __builtin_amdgcn_s_setprio(1);
#pragma unroll
          for (int ks = 0; ks < 2; ++ks) {
            const int cq = ks * 4 + quad;
            s8v a[8], bb[4];
#pragma unroll
            for (int mt = 0; mt < 8; ++mt) {
              int r = mt * 16 + lane15 + kw;  // shifted by kw; halo rows are zero
              a[mt] = *(const s8v*)&lA[abase + (r * 8 + (cq ^ (r & 7))) * 8];
            }
#pragma unroll
            for (int nt = 0; nt < 4; ++nt) {
              int n = (wn << 6) + nt * 16 + lane15;
              bb[nt] = *(const s8v*)&lB[bcur][(n * 8 + (cq ^ (n & 7))) * 8];
            }
#pragma unroll
            for (int mt = 0; mt < 8; ++mt)
#pragma unroll
              for (int nt = 0; nt < 4; ++nt)
                acc[mt][nt] = __builtin_amdgcn_mfma_f32_16x16x32_bf16(a[mt], bb[nt], acc[mt][nt], 0, 0, 0);
          }
          __builtin_amdgcn_s_setprio(0);
        }
        if (pos == 24 && cb < 3) block_barrier();  // protect cb-boundary lA re-prime (WAR)
        bcur = bnext;
      }
    }
  }

  // ---- epilogue: direct stores from acc (D: cout=lane&15, ow=mt*16+quad*4+reg) + stats
  const int oh = oh0 + wm;
#pragma unroll
  for (int nt = 0; nt < 4; ++nt) {
    const int n = (wn << 6) + nt * 16 + lane15;
    float* oc = out + ((size_t)(b * 128 + n) * 128 + oh) * 128;
    float s = 0.f, ss = 0.f;
#pragma unroll
    for (int mt = 0; mt < 8; ++mt) {
      f4v v = acc[mt][nt];
      *(f4v*)&oc[mt * 16 + (quad << 2)] = v;
      s += v.x + v.y + v.z + v.w;
      ss += v.x * v.x + v.y * v.y + v.z * v.z + v.w * v.w;
    }
    s += __shfl_xor(s, 16, 64); ss += __shfl_xor(ss, 16, 64);
    s += __shfl_xor(s, 32, 64); ss += __shfl_xor(ss, 32, 64);
    if (quad == 0) { atomicAdd(&lsum[n], s); atomicAdd(&lssq[n], ss); }
  }
  __syncthreads();
  if (tid < 128) {
    atomicAdd(&gstats[tid], lsum[tid]);
    atomicAdd(&gstats[128 + tid], lssq[tid]);
  }
}

// ---------------- Normalize + ReLU in-place, grid-stride ----------------
__global__ __launch_bounds__(256) void norm_kernel(float* __restrict__ out,
                                                   const float* __restrict__ gstats,
                                                   const float* __restrict__ gamma,
                                                   const float* __restrict__ beta) {
  for (int i = blockIdx.x * 256 + threadIdx.x; i < 4194304; i += 2048 * 256) {
    f4v v = ((f4v*)out)[i];
    int c = (i >> 12) & 127;
    float mean = gstats[c] * (1.f / 131072.f);
    float var = gstats[128 + c] * (1.f / 131072.f) - mean * mean;
    float sc = gamma[c] * rsqrtf(var + 1e-5f);
    float bi = beta[c] - mean * sc;
    v.x = fmaxf(fmaf(v.x, sc, bi), 0.f);
    v.y = fmaxf(fmaf(v.y, sc, bi), 0.f);
    v.z = fmaxf(fmaf(v.z, sc, bi), 0.f);
    v.w = fmaxf(fmaf(v.w, sc, bi), 0.f);
    ((f4v*)out)[i] = v;
  }
}

extern "C" void kernel_launch(void* const* d_in, const int* in_sizes, int n_in,
                              void* d_out, int out_size, void* d_ws, size_t ws_size,
                              hipStream_t stream) {
  (void)in_sizes; (void)n_in; (void)out_size; (void)ws_size;
  const float* x = (const float*)d_in[0];
  const float* W = (const float*)d_in[1];
  const float* gamma = (const float*)d_in[2];
  const float* beta = (const float*)d_in[3];
  float* out = (float*)d_out;
  char* ws = (char*)d_ws;
  __hip_bfloat16* up = (__hip_bfloat16*)ws;                       // 67,108,864 B
  __hip_bfloat16* Wr = (__hip_bfloat16*)(ws + 67108864);          // 1,638,400 B
  float* gstats = (float*)(ws + 67108864 + 1638400);              // sum[128], ssq[128]

  upsample_kernel<<<1024, 256, 0, stream>>>(x, up, W, Wr, gstats);  // + wpack + gstats zero
  conv_kernel<<<256, 512, 0, stream>>>(up, Wr, out, gstats);
  norm_kernel<<<2048, 256, 0, stream>>>(out, gstats, gamma, beta);
}